// Round 7
// baseline (587.083 us; speedup 1.0000x reference)
//
#include <hip/hip_runtime.h>

namespace {

typedef float f32x4 __attribute__((ext_vector_type(4)));
typedef short bf16x8 __attribute__((ext_vector_type(8)));

constexpr float SM_SCALE = 0.08838834764831845f; // 1/sqrt(128)

#define MFMA16(a, b, c) __builtin_amdgcn_mfma_f32_16x16x32_bf16((a), (b), (c), 0, 0, 0)

__device__ __forceinline__ unsigned short bf16_rne(float x) {
  unsigned u = __float_as_uint(x);
  u += 0x7fffu + ((u >> 16) & 1u);
  return (unsigned short)(u >> 16);
}
__device__ __forceinline__ float bf16f(unsigned short h) {
  return __uint_as_float(((unsigned)h) << 16);
}
__device__ __forceinline__ void gld16(const void* g, void* l) {
  __builtin_amdgcn_global_load_lds(
      (const __attribute__((address_space(1))) unsigned int*)g,
      (__attribute__((address_space(3))) unsigned int*)l, 16, 0, 0);
}
__device__ __forceinline__ uint4 pack8(const unsigned short* h) {
  uint4 u;
  u.x = (unsigned)h[0] | ((unsigned)h[1] << 16);
  u.y = (unsigned)h[2] | ((unsigned)h[3] << 16);
  u.z = (unsigned)h[4] | ((unsigned)h[5] << 16);
  u.w = (unsigned)h[6] | ((unsigned)h[7] << 16);
  return u;
}
// pack 8 fp32 -> hi/lo bf16x8
__device__ __forceinline__ void split8(const float4& a, const float4& b,
                                       bf16x8* hi, bf16x8* lo) {
  unsigned short h[8], ll[8];
  const float f[8] = {a.x, a.y, a.z, a.w, b.x, b.y, b.z, b.w};
#pragma unroll
  for (int j = 0; j < 8; ++j) {
    h[j] = bf16_rne(f[j]);
    ll[j] = bf16_rne(f[j] - bf16f(h[j]));
  }
  uint4 uh = pack8(h), ul = pack8(ll);
  *hi = *(const bf16x8*)&uh;
  *lo = *(const bf16x8*)&ul;
}

// ---------------------------------------------------------------------------
// prep_w: W[2048][128] fp32 -> Wt_hi/Wt_lo [3][128][2048] bf16 (transposed).
// ---------------------------------------------------------------------------
__global__ void prep_w(const float* __restrict__ Wq, const float* __restrict__ Wk,
                       const float* __restrict__ Wv,
                       unsigned short* __restrict__ WtH, unsigned short* __restrict__ WtL) {
  const int tg = blockIdx.x * 256 + threadIdx.x;   // 0..98303
  const int mi = tg >> 15;                          // 0=q 1=k 2=v
  const int rem = tg & 32767;
  const int n = rem & 127;
  const int k0 = (rem >> 7) * 8;
  const float* W = (mi == 0) ? Wq : ((mi == 1) ? Wk : Wv);
  unsigned short hv[8], lv[8];
#pragma unroll
  for (int e = 0; e < 8; ++e) {
    float xx = W[(size_t)(k0 + e) * 128 + n];
    unsigned short hh = bf16_rne(xx);
    hv[e] = hh;
    lv[e] = bf16_rne(xx - bf16f(hh));
  }
  const size_t off = (size_t)mi * 262144 + (size_t)n * 2048 + k0;
  *(uint4*)(WtH + off) = pack8(hv);
  *(uint4*)(WtL + off) = pack8(lv);
}

// ---------------------------------------------------------------------------
// qkv_gemm v5: BARRIER-FREE split-bf16 MFMA GEMM. BM=64, BN=128, BK=32/iter.
// All operands loaded global->reg per fragment (W is L2-resident; x frag
// reads are full-line). No LDS in the K-loop; LDS only for the coalesced
// epilogue. Grid 768 x 4 waves = 3/SIMD, all resident, no tail.
// ---------------------------------------------------------------------------
__global__ __launch_bounds__(256, 3) void qkv_gemm(
    const float* __restrict__ x,
    const unsigned short* __restrict__ WtH, const unsigned short* __restrict__ WtL,
    const float* __restrict__ bq, const float* __restrict__ bk, const float* __restrict__ bv,
    unsigned short* __restrict__ qh, unsigned short* __restrict__ ql,
    unsigned short* __restrict__ kh, unsigned short* __restrict__ kl,
    unsigned short* __restrict__ vTh, unsigned short* __restrict__ vTl) {
  __shared__ __align__(16) float Cb[64 * 128];   // 32 KB, epilogue only

  const int bid = blockIdx.x;
  const int L = 96 * (bid & 7) + (bid >> 3);   // XCD-chunk; trio {3j..3j+2} same XCD
  const int mi = L % 3;
  const int m0 = (L / 3) * 64;
  const int t = threadIdx.x;
  const int w = t >> 6, l = t & 63, g = l >> 4, lm = l & 15;
  const int wr = w >> 1, wc = w & 1;
  const unsigned short* WhP = WtH + (size_t)mi * 262144;
  const unsigned short* WlP = WtL + (size_t)mi * 262144;
  const float* bias = (mi == 0) ? bq : ((mi == 1) ? bk : bv);

  // per-lane fragment bases
  const float* xr0 = x + (size_t)(m0 + wr * 32 + lm) * 2048 + g * 8;        // m=0 row
  const float* xr1 = x + (size_t)(m0 + wr * 32 + 16 + lm) * 2048 + g * 8;   // m=1 row
  size_t wo[4];
#pragma unroll
  for (int n = 0; n < 4; ++n)
    wo[n] = (size_t)(wc * 64 + n * 16 + lm) * 2048 + g * 8;

  const f32x4 zf = {0.f, 0.f, 0.f, 0.f};
  f32x4 acc[2][4];
#pragma unroll
  for (int m = 0; m < 2; ++m)
#pragma unroll
    for (int n = 0; n < 4; ++n) acc[m][n] = zf;

#pragma unroll 2
  for (int kc = 0; kc < 2048; kc += 32) {
    // ---- load fragments (12 VMEM, no LDS, no barriers) ----
    const float4 a0a = *(const float4*)(xr0 + kc);
    const float4 a0b = *(const float4*)(xr0 + kc + 4);
    const float4 a1a = *(const float4*)(xr1 + kc);
    const float4 a1b = *(const float4*)(xr1 + kc + 4);
    bf16x8 bh[4], bl[4];
#pragma unroll
    for (int n = 0; n < 4; ++n) {
      bh[n] = *(const bf16x8*)(WhP + wo[n] + kc);
      bl[n] = *(const bf16x8*)(WlP + wo[n] + kc);
    }
    // ---- convert A in-reg ----
    bf16x8 ah0, al0, ah1, al1;
    split8(a0a, a0b, &ah0, &al0);
    split8(a1a, a1b, &ah1, &al1);
    // ---- 24 MFMA ----
#pragma unroll
    for (int n = 0; n < 4; ++n) {
      acc[0][n] = MFMA16(ah0, bh[n], acc[0][n]);
      acc[0][n] = MFMA16(ah0, bl[n], acc[0][n]);
      acc[0][n] = MFMA16(al0, bh[n], acc[0][n]);
      acc[1][n] = MFMA16(ah1, bh[n], acc[1][n]);
      acc[1][n] = MFMA16(ah1, bl[n], acc[1][n]);
      acc[1][n] = MFMA16(al1, bh[n], acc[1][n]);
    }
  }

  // ---- epilogue: C -> LDS fp32, then coalesced 16B stores ----
#pragma unroll
  for (int n = 0; n < 4; ++n) {
    const int col = wc * 64 + n * 16 + lm;
    const float bn = bias[col];
#pragma unroll
    for (int m = 0; m < 2; ++m)
#pragma unroll
      for (int r = 0; r < 4; ++r)
        Cb[(wr * 32 + m * 16 + g * 4 + r) * 128 + col] = acc[m][n][r] + bn;
  }
  __syncthreads();

  if (mi < 2) {
    unsigned short* oh = (mi == 0) ? qh : kh;
    unsigned short* ol = (mi == 0) ? ql : kl;
    const int c8 = (t & 15) * 8;
#pragma unroll
    for (int i = 0; i < 4; ++i) {
      const int row = i * 16 + (t >> 4);
      float v8[8];
      *(float4*)(v8)     = *(const float4*)&Cb[row * 128 + c8];
      *(float4*)(v8 + 4) = *(const float4*)&Cb[row * 128 + c8 + 4];
      unsigned short h8[8], l8[8];
#pragma unroll
      for (int j = 0; j < 8; ++j) {
        h8[j] = bf16_rne(v8[j]);
        l8[j] = bf16_rne(v8[j] - bf16f(h8[j]));
      }
      const size_t o = (size_t)(m0 + row) * 128 + c8;
      *(uint4*)(oh + o) = pack8(h8);
      *(uint4*)(ol + o) = pack8(l8);
    }
  } else {
    const int bidx = m0 >> 12, tb0 = m0 & 4095;
    const int tc8 = (t & 7) * 8;
#pragma unroll
    for (int i = 0; i < 4; ++i) {
      const int h = i * 32 + (t >> 3);
      float v8[8];
#pragma unroll
      for (int j = 0; j < 8; ++j) v8[j] = Cb[(tc8 + j) * 128 + h];
      unsigned short h8[8], l8[8];
#pragma unroll
      for (int j = 0; j < 8; ++j) {
        h8[j] = bf16_rne(v8[j]);
        l8[j] = bf16_rne(v8[j] - bf16f(h8[j]));
      }
      const size_t o = ((size_t)bidx * 128 + h) * 4096 + tb0 + tc8;
      *(uint4*)(vTh + o) = pack8(h8);
      *(uint4*)(vTl + o) = pack8(l8);
    }
  }
}

// ---------------------------------------------------------------------------
// attn (round-5 proven version): BQ=64 (4 waves x 16 q-rows), BK=64,
// qb-pairing (pj, 63-pj) + kv-split-4 -> 512 blocks, uniform 32-33 tiles.
// K/V staged via global_load_lds (pre-swizzled source); swizzled LDS reads.
// ---------------------------------------------------------------------------
__global__ __launch_bounds__(256, 2) void attn(
    const unsigned short* __restrict__ qh, const unsigned short* __restrict__ ql,
    const unsigned short* __restrict__ kh, const unsigned short* __restrict__ kl,
    const unsigned short* __restrict__ vTh, const unsigned short* __restrict__ vTl,
    float* __restrict__ OP, float* __restrict__ ML) {
  __shared__ __align__(16) unsigned short sm[40960];  // 80 KB
  unsigned short* KhL = sm;            // [64][128] swz
  unsigned short* KlL = sm + 8192;
  unsigned short* VhL = sm + 16384;    // [128][64] swz (h-major)
  unsigned short* VlL = sm + 24576;
  unsigned short* PhL = sm + 32768;    // [4 waves][16][64] swz
  unsigned short* PlL = sm + 36864;

  const int b = blockIdx.y, bx = blockIdx.x;
  const int pj = bx >> 2, s = bx & 3;
  const int t = threadIdx.x, w = t >> 6, l = t & 63, g = l >> 4, lm = l & 15;
  const int sw8 = (lm & 7) << 3;
  const size_t bT = (size_t)b * 4096;
  const f32x4 zf = {0.f, 0.f, 0.f, 0.f};

  const int krow_l = l >> 4;   // K: block j covers kv rows 4j..4j+3
  const int kh8 = (l & 15) * 8;
  const int vrow_l = l >> 3;   // V: block j covers h rows 8j..8j+7
  const int vk8 = (l & 7) * 8;

  for (int pass = 0; pass < 2; ++pass) {
    const int qb = pass ? (63 - pj) : pj;         // bijective over 0..63
    const int q0 = qb * 64;
    const int part = b * 256 + qb * 4 + s;

    bf16x8 qfh[4], qfl[4];
    const size_t qoff = (bT + q0 + w * 16 + lm) * 128;
#pragma unroll
    for (int ks = 0; ks < 4; ++ks) {
      qfh[ks] = *(const bf16x8*)(qh + qoff + ks * 32 + g * 8);
      qfl[ks] = *(const bf16x8*)(ql + qoff + ks * 32 + g * 8);
    }

    f32x4 o[8];
#pragma unroll
    for (int n = 0; n < 8; ++n) o[n] = zf;
    float mrow = -1e30f, lrow = 0.f;
    const int qg = q0 + w * 16 + lm;
    const int nt = qb + 1;   // BK=64 tiles

    for (int ti = s; ti < nt; ti += 4) {
      const int t0 = ti * 64;
      __syncthreads();   // previous tile/pass done reading LDS
#pragma unroll
      for (int i = 0; i < 4; ++i) {
        const int j = w * 4 + i;                    // 1KB block 0..15
        const int krow = 4 * j + krow_l;
        const size_t kgo = (bT + t0 + krow) * 128 + (kh8 ^ ((krow & 7) << 3));
        gld16(kh + kgo, KhL + j * 512);
        gld16(kl + kgo, KlL + j * 512);
        const int hrow = 8 * j + vrow_l;
        const size_t vgo = ((size_t)b * 128 + hrow) * 4096 + t0 + (vk8 ^ ((hrow & 7) << 3));
        gld16(vTh + vgo, VhL + j * 512);
        gld16(vTl + vgo, VlL + j * 512);
      }
      __syncthreads();   // DMA drained, K/V staged

      f32x4 sa[4] = {zf, zf, zf, zf};
      __builtin_amdgcn_s_setprio(1);
#pragma unroll
      for (int ks = 0; ks < 4; ++ks) {
        const int kb = (ks * 32 + g * 8) ^ sw8;
#pragma unroll
        for (int m = 0; m < 4; ++m) {
          const bf16x8 kf = *(const bf16x8*)&KhL[(m * 16 + lm) * 128 + kb];
          const bf16x8 lf = *(const bf16x8*)&KlL[(m * 16 + lm) * 128 + kb];
          sa[m] = MFMA16(kf, qfh[ks], sa[m]);
          sa[m] = MFMA16(kf, qfl[ks], sa[m]);
          sa[m] = MFMA16(lf, qfh[ks], sa[m]);
        }
      }
      __builtin_amdgcn_s_setprio(0);

      float pv_[16];
      float mt = -1e30f;
#pragma unroll
      for (int m = 0; m < 4; ++m)
#pragma unroll
        for (int r = 0; r < 4; ++r) {
          const int kvg = t0 + m * 16 + g * 4 + r;
          const float sv = (kvg <= qg) ? sa[m][r] * SM_SCALE : -1e30f;
          pv_[m * 4 + r] = sv;
          mt = fmaxf(mt, sv);
        }
      mt = fmaxf(mt, __shfl_xor(mt, 16));
      mt = fmaxf(mt, __shfl_xor(mt, 32));
      const float mnew = fmaxf(mrow, mt);
      const float sc = __expf(mrow - mnew);
      float lsum = 0.f;
#pragma unroll
      for (int j = 0; j < 16; ++j) {
        const float pe = (pv_[j] > -9e29f) ? __expf(pv_[j] - mnew) : 0.f;
        pv_[j] = pe;
        lsum += pe;
      }
      lsum += __shfl_xor(lsum, 16);
      lsum += __shfl_xor(lsum, 32);
      lrow = lrow * sc + lsum;
      mrow = mnew;
      float scr[4];
#pragma unroll
      for (int r = 0; r < 4; ++r) scr[r] = __shfl(sc, g * 4 + r);
#pragma unroll
      for (int n = 0; n < 8; ++n)
#pragma unroll
        for (int r = 0; r < 4; ++r) o[n][r] *= scr[r];

      const int wb = w * 1024;
#pragma unroll
      for (int m = 0; m < 4; ++m)
#pragma unroll
        for (int j2 = 0; j2 < 2; ++j2) {
          const int kv0 = m * 16 + g * 4 + j2 * 2;
          const float p0f = pv_[m * 4 + j2 * 2];
          const float p1f = pv_[m * 4 + j2 * 2 + 1];
          ushort2 h2, l2;
          h2.x = bf16_rne(p0f); l2.x = bf16_rne(p0f - bf16f(h2.x));
          h2.y = bf16_rne(p1f); l2.y = bf16_rne(p1f - bf16f(h2.y));
          *(ushort2*)&PhL[wb + lm * 64 + (kv0 ^ sw8)] = h2;
          *(ushort2*)&PlL[wb + lm * 64 + (kv0 ^ sw8)] = l2;
        }
      const bf16x8 pAh0 = *(const bf16x8*)&PhL[wb + lm * 64 + ((g * 8) ^ sw8)];
      const bf16x8 pAl0 = *(const bf16x8*)&PlL[wb + lm * 64 + ((g * 8) ^ sw8)];
      const bf16x8 pAh1 = *(const bf16x8*)&PhL[wb + lm * 64 + ((32 + g * 8) ^ sw8)];
      const bf16x8 pAl1 = *(const bf16x8*)&PlL[wb + lm * 64 + ((32 + g * 8) ^ sw8)];

      __builtin_amdgcn_s_setprio(1);
#pragma unroll
      for (int n = 0; n < 8; ++n) {
        const int vb = (n * 16 + lm) * 64;
        const bf16x8 vh0 = *(const bf16x8*)&VhL[vb + ((g * 8) ^ sw8)];
        const bf16x8 vl0 = *(const bf16x8*)&VlL[vb + ((g * 8) ^ sw8)];
        o[n] = MFMA16(pAh0, vh0, o[n]);
        o[n] = MFMA16(pAh0, vl0, o[n]);
        o[n] = MFMA16(pAl0, vh0, o[n]);
        const bf16x8 vh1 = *(const bf16x8*)&VhL[vb + ((32 + g * 8) ^ sw8)];
        const bf16x8 vl1 = *(const bf16x8*)&VlL[vb + ((32 + g * 8) ^ sw8)];
        o[n] = MFMA16(pAh1, vh1, o[n]);
        o[n] = MFMA16(pAh1, vl1, o[n]);
        o[n] = MFMA16(pAl1, vh1, o[n]);
      }
      __builtin_amdgcn_s_setprio(0);
    } // kv tiles

    float* OPp = OP + (size_t)part * 8192;
#pragma unroll
    for (int n = 0; n < 8; ++n)
#pragma unroll
      for (int r = 0; r < 4; ++r)
        OPp[(size_t)(w * 16 + g * 4 + r) * 128 + n * 16 + lm] = o[n][r];
    if (l < 16) {
      ML[((size_t)part * 64 + w * 16 + l) * 2 + 0] = mrow;
      ML[((size_t)part * 64 + w * 16 + l) * 2 + 1] = lrow;
    }
  } // pass
}

// ---------------------------------------------------------------------------
// combine: merge the 4 kv-split partials per q-row. 256 blocks x 256 thr.
// ---------------------------------------------------------------------------
__global__ void combine(const float* __restrict__ OP, const float* __restrict__ ML,
                        float* __restrict__ out) {
  const int x = blockIdx.x;
  const int b = x >> 6, qb = x & 63;
  const int p0 = b * 256 + qb * 4;
  const int t = threadIdx.x;
  const int r = t >> 2, hq = (t & 3) * 32;
  float m[4], ll[4];
#pragma unroll
  for (int s2 = 0; s2 < 4; ++s2) {
    m[s2]  = ML[((size_t)(p0 + s2) * 64 + r) * 2 + 0];
    ll[s2] = ML[((size_t)(p0 + s2) * 64 + r) * 2 + 1];
  }
  const float mx = fmaxf(fmaxf(m[0], m[1]), fmaxf(m[2], m[3]));
  float wgt[4], den = 0.f;
#pragma unroll
  for (int s2 = 0; s2 < 4; ++s2) {
    wgt[s2] = __expf(m[s2] - mx);
    den += wgt[s2] * ll[s2];
  }
  const float inv = 1.f / den;
  float* op = out + ((size_t)(b * 4096 + qb * 64 + r)) * 128 + hq;
#pragma unroll
  for (int j = 0; j < 8; ++j) {
    float ax = 0.f, ay = 0.f, az = 0.f, aw = 0.f;
#pragma unroll
    for (int s2 = 0; s2 < 4; ++s2) {
      const float4 pv = *(const float4*)(OP + ((size_t)(p0 + s2) * 64 + r) * 128 + hq + j * 4);
      ax += wgt[s2] * pv.x; ay += wgt[s2] * pv.y;
      az += wgt[s2] * pv.z; aw += wgt[s2] * pv.w;
    }
    float4 ov; ov.x = ax * inv; ov.y = ay * inv; ov.z = az * inv; ov.w = aw * inv;
    *(float4*)(op + j * 4) = ov;
  }
}

}  // namespace

extern "C" void kernel_launch(void* const* d_in, const int* in_sizes, int n_in,
                              void* d_out, int out_size, void* d_ws, size_t ws_size,
                              hipStream_t stream) {
  // setup_inputs order: x, Wk, bk, Wq, bq, Wv, bv
  const float* x  = (const float*)d_in[0];
  const float* Wk = (const float*)d_in[1];
  const float* bk = (const float*)d_in[2];
  const float* Wq = (const float*)d_in[3];
  const float* bq = (const float*)d_in[4];
  const float* Wv = (const float*)d_in[5];
  const float* bv = (const float*)d_in[6];
  float* out = (float*)d_out;

  // workspace carve (~62 MB, same as round 5)
  unsigned short* WtH = (unsigned short*)d_ws;           // 3*128*2048
  unsigned short* WtL = WtH + 786432;
  unsigned short* qh  = WtL + 786432;                    // [16384][128] each
  unsigned short* ql  = qh + 2097152;
  unsigned short* kh  = ql + 2097152;
  unsigned short* kl  = kh + 2097152;
  unsigned short* vTh = kl + 2097152;                    // [4][128][4096]
  unsigned short* vTl = vTh + 2097152;
  float* OP = (float*)(vTl + 2097152);                   // [1024][64][128]
  float* ML = OP + (size_t)1024 * 8192;                  // [1024][64][2]

  prep_w<<<384, 256, 0, stream>>>(Wq, Wk, Wv, WtH, WtL);
  qkv_gemm<<<768, 256, 0, stream>>>(x, WtH, WtL, bq, bk, bv,
                                    qh, ql, kh, kl, vTh, vTl);
  attn<<<dim3(256, 4), 256, 0, stream>>>(qh, ql, kh, kl, vTh, vTl, OP, ML);
  combine<<<256, 256, 0, stream>>>(OP, ML, out);
}